// Round 1
// baseline (255.923 us; speedup 1.0000x reference)
//
#include <hip/hip_runtime.h>

// MaskedDenseLayer (MADE-style): out[b,o] = relu(sum_i x[b,i]*kernel[i,o]*masks[state[b],i,o] + b0[o])
// BS=512, IN_DIM=784, OUT_DIM=1024, N_MASKS=16, all fp32.
//
// Strategy: group samples by state (16 groups, ~32 samples each) so each
// (state, o-tile) block reads its mask/kernel tile exactly once.
// Grid: 16 states x 16 o-tiles (64 cols) = 256 blocks, 512 threads (8 waves).
// Lane = output column (64), wave = i-range (784/8 = 98 each).
// Each thread: NB=32 fp32 accumulators over the state's samples.
// x[b,i] is wave-uniform -> readfirstlane forces scalar (s_load) path.
// Cross-wave reduction over the 8 i-groups via padded LDS (stride 17 words).

#define BS 512
#define IN_DIM 784
#define OUT_DIM 1024
#define N_MASKS 16
#define NB 32          // samples per chunk (accumulators per thread)
#define NIG 8          // i-groups (one per wave)
#define OT 64          // output columns per block
#define IR (IN_DIM / NIG)  // 98 i's per wave

__global__ __launch_bounds__(512, 2) void made_masked_dense(
    const float* __restrict__ x,      // [BS, IN_DIM]
    const int*   __restrict__ state,  // [BS]
    const float* __restrict__ masks,  // [N_MASKS, IN_DIM, OUT_DIM]
    const float* __restrict__ kern,   // [IN_DIM, OUT_DIM]
    const float* __restrict__ b0,     // [OUT_DIM]
    float*       __restrict__ out)    // [BS, OUT_DIM]
{
    __shared__ int   list[BS];
    __shared__ int   cnt;
    __shared__ float red[NIG][OT][17];   // +1 word pad -> stride 17, conflict-free

    const int tid  = threadIdx.x;
    const int s    = blockIdx.x & 15;    // state
    const int ot   = blockIdx.x >> 4;    // o-tile
    const int lane = tid & 63;           // output column within tile
    const int ig   = tid >> 6;           // i-group (wave id)
    const int og   = ot * OT + lane;     // global output column

    if (tid == 0) cnt = 0;
    __syncthreads();
    {   // build this state's sample list (order varies; output is order-independent)
        int st = state[tid];             // 512 threads == BS
        if (st == s) { int p = atomicAdd(&cnt, 1); list[p] = tid; }
    }
    __syncthreads();
    const int ns = cnt;

    const int i0 = ig * IR;
    const float* kp = kern  + og;
    const float* mp = masks + (size_t)s * IN_DIM * OUT_DIM + og;

    for (int base = 0; base < ns; base += NB) {
        // sample row offsets, forced wave-uniform (SGPR) for scalar x loads
        int off[NB];
#pragma unroll
        for (int j = 0; j < NB; ++j) {
            int idx = base + j;
            if (idx >= ns) idx = ns - 1;            // clamp; store is guarded below
            off[j] = __builtin_amdgcn_readfirstlane(list[idx]) * IN_DIM;
        }

        float acc[NB];
#pragma unroll
        for (int j = 0; j < NB; ++j) acc[j] = 0.f;

        for (int i = i0; i < i0 + IR; i += 2) {
            float k0 = kp[(size_t)i * OUT_DIM];
            float k1 = kp[(size_t)(i + 1) * OUT_DIM];
            float m0 = mp[(size_t)i * OUT_DIM];
            float m1 = mp[(size_t)(i + 1) * OUT_DIM];
            float w0 = k0 * m0, w1 = k1 * m1;
#pragma unroll
            for (int j = 0; j < NB; ++j) {
                const float* xp = x + off[j] + i;   // uniform address -> s_load
                float x0 = xp[0], x1 = xp[1];
                acc[j] = fmaf(x0, w0, acc[j]);
                acc[j] = fmaf(x1, w1, acc[j]);
            }
        }

        // reduce the 8 i-group partials; two slices of 16 samples to cap LDS
        for (int r0 = 0; r0 < NB; r0 += 16) {
            __syncthreads();  // protect red[] from previous slice's readers
#pragma unroll
            for (int j = 0; j < 16; ++j) red[ig][lane][j] = acc[r0 + j];
            __syncthreads();
            // 64 o x 16 j = 1024 outputs over 512 threads -> 2 each
#pragma unroll
            for (int rep = 0; rep < 2; ++rep) {
                int idx = tid + rep * 512;
                int j = idx & 15;
                int o = idx >> 4;
                float sum = 0.f;
#pragma unroll
                for (int g = 0; g < NIG; ++g) sum += red[g][o][j];
                int sj = base + r0 + j;
                if (sj < ns) {
                    int b = list[sj];
                    float v = sum + b0[ot * OT + o];
                    out[(size_t)b * OUT_DIM + ot * OT + o] = v > 0.f ? v : 0.f;
                }
            }
        }
    }
}

extern "C" void kernel_launch(void* const* d_in, const int* in_sizes, int n_in,
                              void* d_out, int out_size, void* d_ws, size_t ws_size,
                              hipStream_t stream) {
    const float* x     = (const float*)d_in[0];
    const int*   state = (const int*)  d_in[1];
    const float* masks = (const float*)d_in[2];
    const float* kern  = (const float*)d_in[3];
    const float* b0    = (const float*)d_in[4];
    float* out = (float*)d_out;

    made_masked_dense<<<dim3(256), dim3(512), 0, stream>>>(x, state, masks, kern, b0, out);
}

// Round 2
// 35.171 us; speedup vs baseline: 7.2764x; 7.2764x over previous
//
#include <hip/hip_runtime.h>
#include <hip/hip_bf16.h>

// MaskedDenseLayer via grouped bf16 MFMA.
// out[b,o] = relu(sum_i x[b,i] * kernel[i,o] * masks[state[b],i,o] + b0[o])
// Grouped by state: per state s it's a GEMM with W_s = kernel .* masks[s],
// M = ns (~32 samples), N = 1024, K = 784.
//
// Grid: 256 blocks = (state 16) x (o-tile 16 of 64 cols). 512 thr = 8 waves.
// Wave w: nsl = w&1 (32-col slice), kq = w>>2.. (4-way K split, 6 steps of 32
// each; kq==3 also does the 16-wide tail at i=768). mfma_f32_16x16x32_bf16,
// M=32 (2 A-frags), N=32 (2 B-frags), acc[2][2] f32x4.
// A: lane holds row=lane&15, k=8*(lane>>4)+e (contiguous -> 2 float4 loads).
// B: lane holds col=lane&15, k=8*(lane>>4)+e (stride-4KB dword loads of k*m).
// C/D: col=lane&15, row=(lane>>4)*4+reg  [m89-verified layout].
// K-quarters reduced through LDS [16][64] (lane-contiguous, conflict-free).

#define BS 512
#define IN_DIM 784
#define OUT_DIM 1024
#define N_MASKS 16

typedef __attribute__((ext_vector_type(8))) short bf16x8;
typedef __attribute__((ext_vector_type(4))) float f32x4;

static __device__ inline short f2bf(float f) {
    __hip_bfloat16 h = __float2bfloat16(f);   // RNE
    short r; __builtin_memcpy(&r, &h, 2); return r;
}

__global__ __launch_bounds__(512, 1) void made_mfma(
    const float* __restrict__ x,      // [BS, IN_DIM]
    const int*   __restrict__ state,  // [BS]
    const float* __restrict__ masks,  // [N_MASKS, IN_DIM, OUT_DIM]
    const float* __restrict__ kern,   // [IN_DIM, OUT_DIM]
    const float* __restrict__ bias,   // [OUT_DIM]
    float*       __restrict__ out)    // [BS, OUT_DIM]
{
    __shared__ int   list[BS];
    __shared__ int   cnt;
    __shared__ float red[3][2][16][64];  // [kq-1][nsl][accidx][lane] 24 KB

    const int tid  = threadIdx.x;
    const int s    = blockIdx.x & 15;
    const int ot   = blockIdx.x >> 4;
    const int lane = tid & 63;
    const int w    = tid >> 6;
    const int nsl  = w & 1;
    const int kq   = w >> 1;        // 0..3

    if (tid == 0) cnt = 0;
    __syncthreads();
    { int st = state[tid]; if (st == s) { int p = atomicAdd(&cnt, 1); list[p] = tid; } }
    __syncthreads();
    const int ns = cnt;

    const int l15   = lane & 15;
    const int lg    = lane >> 4;          // k-subgroup 0..3
    const int obase = ot * 64 + nsl * 32;

    // B per-lane base: row lg*8, col obase+l15
    const size_t bcol0 = (size_t)(lg * 8) * OUT_DIM + (obase + l15);
    const float* kp = kern + bcol0;
    const float* mp = masks + (size_t)s * IN_DIM * OUT_DIM + bcol0;

    for (int base = 0; base < ns; base += 32) {
        int i0c = base + l15;       if (i0c >= ns) i0c = ns - 1;
        int i1c = base + 16 + l15;  if (i1c >= ns) i1c = ns - 1;
        const float* xr0 = x + (size_t)list[i0c] * IN_DIM + lg * 8;
        const float* xr1 = x + (size_t)list[i1c] * IN_DIM + lg * 8;

        f32x4 acc[2][2];
#pragma unroll
        for (int m = 0; m < 2; ++m)
#pragma unroll
            for (int n = 0; n < 2; ++n)
#pragma unroll
                for (int r = 0; r < 4; ++r) acc[m][n][r] = 0.f;

        const int s0 = kq * 6;
        for (int st6 = 0; st6 < 6; ++st6) {
            const int k0 = (s0 + st6) * 32;
            // ---- A frags ----
            bf16x8 a0, a1;
            {
                float4 pa = *(const float4*)(xr0 + k0);
                float4 pb = *(const float4*)(xr0 + k0 + 4);
                a0[0]=f2bf(pa.x); a0[1]=f2bf(pa.y); a0[2]=f2bf(pa.z); a0[3]=f2bf(pa.w);
                a0[4]=f2bf(pb.x); a0[5]=f2bf(pb.y); a0[6]=f2bf(pb.z); a0[7]=f2bf(pb.w);
                float4 qa = *(const float4*)(xr1 + k0);
                float4 qb = *(const float4*)(xr1 + k0 + 4);
                a1[0]=f2bf(qa.x); a1[1]=f2bf(qa.y); a1[2]=f2bf(qa.z); a1[3]=f2bf(qa.w);
                a1[4]=f2bf(qb.x); a1[5]=f2bf(qb.y); a1[6]=f2bf(qb.z); a1[7]=f2bf(qb.w);
            }
            // ---- B frags (w = kern * mask) ----
            bf16x8 b0, b1;
#pragma unroll
            for (int e = 0; e < 8; ++e) {
                size_t off = (size_t)(k0 + e) * OUT_DIM;
                float w0 = kp[off]      * mp[off];
                float w1 = kp[off + 16] * mp[off + 16];
                b0[e] = f2bf(w0);
                b1[e] = f2bf(w1);
            }
            acc[0][0] = __builtin_amdgcn_mfma_f32_16x16x32_bf16(a0, b0, acc[0][0], 0, 0, 0);
            acc[0][1] = __builtin_amdgcn_mfma_f32_16x16x32_bf16(a0, b1, acc[0][1], 0, 0, 0);
            acc[1][0] = __builtin_amdgcn_mfma_f32_16x16x32_bf16(a1, b0, acc[1][0], 0, 0, 0);
            acc[1][1] = __builtin_amdgcn_mfma_f32_16x16x32_bf16(a1, b1, acc[1][1], 0, 0, 0);
        }

        if (kq == 3) {   // tail: i = 768..783 (16 wide), k-subgroups 0,1 only
            const int k0 = 768;
            bf16x8 a0, a1, b0, b1;
#pragma unroll
            for (int e = 0; e < 8; ++e) { a0[e]=0; a1[e]=0; b0[e]=0; b1[e]=0; }
            if (lg < 2) {
                float4 pa = *(const float4*)(xr0 + k0);
                float4 pb = *(const float4*)(xr0 + k0 + 4);
                a0[0]=f2bf(pa.x); a0[1]=f2bf(pa.y); a0[2]=f2bf(pa.z); a0[3]=f2bf(pa.w);
                a0[4]=f2bf(pb.x); a0[5]=f2bf(pb.y); a0[6]=f2bf(pb.z); a0[7]=f2bf(pb.w);
                float4 qa = *(const float4*)(xr1 + k0);
                float4 qb = *(const float4*)(xr1 + k0 + 4);
                a1[0]=f2bf(qa.x); a1[1]=f2bf(qa.y); a1[2]=f2bf(qa.z); a1[3]=f2bf(qa.w);
                a1[4]=f2bf(qb.x); a1[5]=f2bf(qb.y); a1[6]=f2bf(qb.z); a1[7]=f2bf(qb.w);
#pragma unroll
                for (int e = 0; e < 8; ++e) {
                    size_t off = (size_t)(k0 + e) * OUT_DIM;
                    float w0 = kp[off]      * mp[off];
                    float w1 = kp[off + 16] * mp[off + 16];
                    b0[e] = f2bf(w0);
                    b1[e] = f2bf(w1);
                }
            }
            acc[0][0] = __builtin_amdgcn_mfma_f32_16x16x32_bf16(a0, b0, acc[0][0], 0, 0, 0);
            acc[0][1] = __builtin_amdgcn_mfma_f32_16x16x32_bf16(a0, b1, acc[0][1], 0, 0, 0);
            acc[1][0] = __builtin_amdgcn_mfma_f32_16x16x32_bf16(a1, b0, acc[1][0], 0, 0, 0);
            acc[1][1] = __builtin_amdgcn_mfma_f32_16x16x32_bf16(a1, b1, acc[1][1], 0, 0, 0);
        }

        // ---- reduce across K quarters ----
        if (kq > 0) {
#pragma unroll
            for (int m = 0; m < 2; ++m)
#pragma unroll
                for (int n = 0; n < 2; ++n)
#pragma unroll
                    for (int r = 0; r < 4; ++r)
                        red[kq - 1][nsl][m * 8 + n * 4 + r][lane] = acc[m][n][r];
        }
        __syncthreads();
        if (kq == 0) {
#pragma unroll
            for (int m = 0; m < 2; ++m)
#pragma unroll
                for (int n = 0; n < 2; ++n)
#pragma unroll
                    for (int r = 0; r < 4; ++r) {
                        int idx = m * 8 + n * 4 + r;
                        float v = acc[m][n][r]
                                + red[0][nsl][idx][lane]
                                + red[1][nsl][idx][lane]
                                + red[2][nsl][idx][lane];
                        int ridx = base + m * 16 + lg * 4 + r;
                        if (ridx < ns) {
                            int b = list[ridx];
                            int o = obase + n * 16 + l15;
                            v += bias[o];
                            out[(size_t)b * OUT_DIM + o] = v > 0.f ? v : 0.f;
                        }
                    }
        }
        __syncthreads();   // red[] reused next m-chunk
    }
}

extern "C" void kernel_launch(void* const* d_in, const int* in_sizes, int n_in,
                              void* d_out, int out_size, void* d_ws, size_t ws_size,
                              hipStream_t stream) {
    const float* x     = (const float*)d_in[0];
    const int*   state = (const int*)  d_in[1];
    const float* masks = (const float*)d_in[2];
    const float* kern  = (const float*)d_in[3];
    const float* b0    = (const float*)d_in[4];
    float* out = (float*)d_out;

    made_mfma<<<dim3(256), dim3(512), 0, stream>>>(x, state, masks, kern, b0, out);
}